// Round 6
// baseline (190.759 us; speedup 1.0000x reference)
//
#include <hip/hip_runtime.h>
#include <stdint.h>

#define HW 4096
#define NC 128
#define BATCH 2
#define NBLK 512

typedef __attribute__((ext_vector_type(8))) short bf16x8;
typedef __attribute__((ext_vector_type(4))) float f32x4;
typedef __attribute__((ext_vector_type(8))) unsigned short u16x8;

// Monotonic grid-barrier counter. Module-global (not in poisoned d_ws);
// target = (t/NBLK+1)*NBLK is identical for all blocks of one launch and
// self-consistent across graph replays / rocprof replays (no reset needed).
__device__ unsigned long long g_ctr = 0ULL;

__device__ __forceinline__ unsigned short f32_to_bf16(float f) {
    union { float f; unsigned int u; } v; v.f = f;
    unsigned int u = v.u;
    unsigned int r = (u + 0x7FFFu + ((u >> 16) & 1u)) >> 16;
    return (unsigned short)r;
}

// Async global->LDS, 16B/lane. LDS dest = wave-uniform base + lane*16 (m104).
__device__ __forceinline__ void async_cp16(const void* g, void* s) {
    __builtin_amdgcn_global_load_lds(
        (const __attribute__((address_space(1))) uint32_t*)g,
        (__attribute__((address_space(3))) uint32_t*)s, 16, 0, 0);
}

// Fused: phase 1 = L1-normalize + transpose to [b][pos][c] bf16 (16B-chunk
// swizzle slot = chunk ^ (pos&15) baked into the layout); manual grid barrier
// (co-residency by capacity: 64KB LDS + launch_bounds(256,2) -> exactly
// 2 blocks/CU, grid 512 = 2*256 CUs); phase 2 = persistent-block 128x128 GEMM
// of S = A_n^T (C_n - B_n), A frags in registers, B LDS double-buffered,
// abs-sum -> one atomicAdd per block.
__global__ __launch_bounds__(256, 2) void fused_kernel(
    const float* __restrict__ A, const float* __restrict__ B,
    const float* __restrict__ Cc,
    unsigned short* __restrict__ anT, unsigned short* __restrict__ dT,
    float* __restrict__ out) {
    __shared__ uint4 smem4[4096];  // 64 KB, overlaid: norm-reduce then GEMM bufs
    const int tid = threadIdx.x;
    const int b   = blockIdx.x;    // 0..511

    if (b == 0 && tid == 0) *out = 0.f;  // replaces memset dispatch

    // ---------- Phase 1: norm + transpose (16 positions per block) ----------
    {
        const int pl = tid & 15;           // position lane 0..15
        const int cg = tid >> 4;           // channel group 0..15 (8 ch each)
        const int gp = b * 16;             // 512*16 = 8192 positions
        const int bb = gp >> 12;           // batch
        const int p  = (gp & (HW - 1)) + pl;
        const size_t base = (size_t)bb * NC * HW + p;  // + c*HW -> x[b][c][p]
        const int c0 = cg * 8;

        float va[8], vb[8], vc[8];
        float sa = 0.f, sb = 0.f, sc = 0.f;
#pragma unroll
        for (int k = 0; k < 8; ++k) {
            size_t idx = base + (size_t)(c0 + k) * HW;
            va[k] = A[idx]; vb[k] = B[idx]; vc[k] = Cc[idx];
            sa += fabsf(va[k]); sb += fabsf(vb[k]); sc += fabsf(vc[k]);
        }
        float* red = (float*)smem4;        // 3*16*16 floats = 3 KB of smem4
        red[(0 * 16 + cg) * 16 + pl] = sa;
        red[(1 * 16 + cg) * 16 + pl] = sb;
        red[(2 * 16 + cg) * 16 + pl] = sc;
        __syncthreads();
        float na = 0.f, nb = 0.f, nc = 0.f;
#pragma unroll
        for (int g = 0; g < 16; ++g) {
            na += red[(0 * 16 + g) * 16 + pl];
            nb += red[(1 * 16 + g) * 16 + pl];
            nc += red[(2 * 16 + g) * 16 + pl];
        }
        const float ra = 1.f / fmaxf(na, 1e-12f);
        const float rb = 1.f / fmaxf(nb, 1e-12f);
        const float rc = 1.f / fmaxf(nc, 1e-12f);

        const size_t obase = ((size_t)bb * HW + p) * NC;
        const int slot = cg ^ pl;          // p&15 == pl (block base is 16-aligned)
        u16x8 xa, xd;
#pragma unroll
        for (int j = 0; j < 8; ++j) {
            xa[j] = f32_to_bf16(va[j] * ra);
            xd[j] = f32_to_bf16(vc[j] * rc - vb[j] * rb);
        }
        *(u16x8*)(anT + obase + slot * 8) = xa;
        *(u16x8*)(dT  + obase + slot * 8) = xd;
    }

    // ---------- Grid barrier (device-scope fence + monotonic counter) -------
    __threadfence();                       // release norm writes, device scope
    __syncthreads();
    if (tid == 0) {
        unsigned long long t = __hip_atomic_fetch_add(
            &g_ctr, 1ULL, __ATOMIC_ACQ_REL, __HIP_MEMORY_SCOPE_AGENT);
        unsigned long long target = (t / (unsigned long long)NBLK + 1ULL) *
                                    (unsigned long long)NBLK;
        while (__hip_atomic_load(&g_ctr, __ATOMIC_ACQUIRE,
                                 __HIP_MEMORY_SCOPE_AGENT) < target)
            __builtin_amdgcn_s_sleep(2);
    }
    __syncthreads();
    __threadfence();                       // acquire side for all threads

    // ---------- Phase 2: persistent-block GEMM ----------
    const int bz = b >> 8;                 // batch
    const int my = (b & 255) >> 3;         // m-tile 0..31
    const int ng = b & 7;                  // n-group: tiles ng*4 .. ng*4+3
    const char* gA  = (const char*)(anT + ((size_t)bz * HW + my * 128) * NC);
    const char* gB0 = (const char*)(dT + ((size_t)bz * HW + ng * 4 * 128) * NC);

    const int wv = tid >> 6;
    const int ln = tid & 63;
    char* buf0 = (char*)smem4;
    char* buf1 = (char*)(smem4 + 2048);

    // Stage A -> buf0, B0 -> buf1 (8 x 16B per thread each, async).
#pragma unroll
    for (int i = 0; i < 8; ++i) {
        const size_t goff = (size_t)(i * 256 + tid) * 16;
        const size_t loff = (size_t)i * 4096 + wv * 1024;  // wave-uniform base
        async_cp16(gA + goff, buf0 + loff);
        async_cp16(gB0 + goff, buf1 + loff);
    }
    __syncthreads();

    const int m16  = ln & 15;
    const int quad = ln >> 4;
    const int wr   = (wv >> 1) * 64;
    const int wc   = (wv & 1) * 64;

    // Hoist this wave's A fragments into registers: 16 x bf16x8 = 64 VGPRs.
    bf16x8 aF[4][4];  // [mi][ks]
#pragma unroll
    for (int ks = 0; ks < 4; ++ks) {
        const int slot = (ks * 4 + quad) ^ m16;
#pragma unroll
        for (int mi = 0; mi < 4; ++mi)
            aF[mi][ks] = *(const bf16x8*)(buf0 + (wr + mi * 16 + m16) * 256 + slot * 16);
    }
    __syncthreads();  // A region free; buf0 becomes B staging

    // Prefetch B1 -> buf0.
#pragma unroll
    for (int i = 0; i < 8; ++i)
        async_cp16(gB0 + 32768 + (size_t)(i * 256 + tid) * 16,
                   buf0 + (size_t)i * 4096 + wv * 1024);

    float s = 0.f;
    for (int j = 0; j < 4; ++j) {
        if (j) {
            __syncthreads();             // drains fill of B_j; frees prev buffer
            if (j < 3) {                 // prefetch B_{j+1} into freed buffer
                char* dst = (j & 1) ? buf1 : buf0;
                const char* src = gB0 + (size_t)(j + 1) * 32768;
#pragma unroll
                for (int i = 0; i < 8; ++i)
                    async_cp16(src + (size_t)(i * 256 + tid) * 16,
                               dst + (size_t)i * 4096 + wv * 1024);
            }
        }
        const char* sB = (j & 1) ? buf0 : buf1;
        f32x4 acc[4][4] = {};
#pragma unroll
        for (int ks = 0; ks < 4; ++ks) {
            const int slot = (ks * 4 + quad) ^ m16;
            bf16x8 bfr[4];
#pragma unroll
            for (int ni = 0; ni < 4; ++ni)
                bfr[ni] = *(const bf16x8*)(sB + (wc + ni * 16 + m16) * 256 + slot * 16);
#pragma unroll
            for (int mi = 0; mi < 4; ++mi)
#pragma unroll
                for (int ni = 0; ni < 4; ++ni)
                    acc[mi][ni] = __builtin_amdgcn_mfma_f32_16x16x32_bf16(
                        aF[mi][ks], bfr[ni], acc[mi][ni], 0, 0, 0);
        }
#pragma unroll
        for (int mi = 0; mi < 4; ++mi)
#pragma unroll
            for (int ni = 0; ni < 4; ++ni)
#pragma unroll
                for (int r = 0; r < 4; ++r)
                    s += fabsf(acc[mi][ni][r]);
    }

#pragma unroll
    for (int off = 32; off > 0; off >>= 1)
        s += __shfl_down(s, off);
    __syncthreads();
    if (ln == 0) ((float*)smem4)[wv] = s;
    __syncthreads();
    if (tid == 0) {
        const float inv = 1.0f / ((float)BATCH * (float)HW * (float)HW);
        float t = ((float*)smem4)[0] + ((float*)smem4)[1] +
                  ((float*)smem4)[2] + ((float*)smem4)[3];
        atomicAdd(out, t * inv);
    }
}

extern "C" void kernel_launch(void* const* d_in, const int* in_sizes, int n_in,
                              void* d_out, int out_size, void* d_ws, size_t ws_size,
                              hipStream_t stream) {
    const float* A  = (const float*)d_in[0];
    const float* B  = (const float*)d_in[1];
    const float* Cc = (const float*)d_in[2];
    float* out = (float*)d_out;
    unsigned short* anT = (unsigned short*)d_ws;                 // 2 MB
    unsigned short* dT  = anT + (size_t)BATCH * HW * NC;         // 2 MB

    fused_kernel<<<dim3(NBLK), dim3(256), 0, stream>>>(A, B, Cc, anT, dT, out);
}

// Round 7
// 112.055 us; speedup vs baseline: 1.7024x; 1.7024x over previous
//
#include <hip/hip_runtime.h>
#include <stdint.h>

#define HW 4096
#define NC 128
#define BATCH 2
#define NBLK 512

typedef __attribute__((ext_vector_type(8))) short bf16x8;
typedef __attribute__((ext_vector_type(4))) float f32x4;
typedef __attribute__((ext_vector_type(8))) unsigned short u16x8;

// Monotonic grid-barrier counter. Module-global (not in poisoned d_ws);
// target = (t/NBLK+1)*NBLK is identical for all blocks of one launch and
// self-consistent across graph replays / rocprof replays (no reset needed).
__device__ unsigned long long g_ctr = 0ULL;

__device__ __forceinline__ unsigned short f32_to_bf16(float f) {
    union { float f; unsigned int u; } v; v.f = f;
    unsigned int u = v.u;
    unsigned int r = (u + 0x7FFFu + ((u >> 16) & 1u)) >> 16;
    return (unsigned short)r;
}

// Async global->LDS, 16B/lane. LDS dest = wave-uniform base + lane*16 (m104).
__device__ __forceinline__ void async_cp16(const void* g, void* s) {
    __builtin_amdgcn_global_load_lds(
        (const __attribute__((address_space(1))) uint32_t*)g,
        (__attribute__((address_space(3))) uint32_t*)s, 16, 0, 0);
}

// Fused: phase 1 = L1-normalize + transpose to [b][pos][c] bf16 (16B-chunk
// swizzle slot = chunk ^ (pos&15) baked into the layout); lightweight grid
// barrier (tid0-only fences; RELAXED polls — R6's all-thread __threadfence +
// per-poll ACQUIRE invalidates caused a 137us device-wide stall); phase 2 =
// persistent-block 128x128 GEMM of S = A_n^T (C_n - B_n), A frags in regs,
// B LDS double-buffered, abs-sum -> one atomicAdd per block.
// Co-residency: 64KB LDS + launch_bounds(256,2) -> exactly 2 blocks/CU,
// grid 512 = 2 x 256 CUs.
__global__ __launch_bounds__(256, 2) void fused_kernel(
    const float* __restrict__ A, const float* __restrict__ B,
    const float* __restrict__ Cc,
    unsigned short* __restrict__ anT, unsigned short* __restrict__ dT,
    float* __restrict__ out) {
    __shared__ uint4 smem4[4096];  // 64 KB, overlaid: norm-reduce then GEMM bufs
    const int tid = threadIdx.x;
    const int b   = blockIdx.x;    // 0..511

    if (b == 0 && tid == 0)        // agent-scope store: no L2 line to clobber later
        __hip_atomic_store(out, 0.f, __ATOMIC_RELAXED, __HIP_MEMORY_SCOPE_AGENT);

    // ---------- Phase 1: norm + transpose (16 positions per block) ----------
    {
        const int pl = tid & 15;           // position lane 0..15
        const int cg = tid >> 4;           // channel group 0..15 (8 ch each)
        const int gp = b * 16;             // 512*16 = 8192 positions
        const int bb = gp >> 12;           // batch
        const int p  = (gp & (HW - 1)) + pl;
        const size_t base = (size_t)bb * NC * HW + p;  // + c*HW -> x[b][c][p]
        const int c0 = cg * 8;

        float va[8], vb[8], vc[8];
        float sa = 0.f, sb = 0.f, sc = 0.f;
#pragma unroll
        for (int k = 0; k < 8; ++k) {
            size_t idx = base + (size_t)(c0 + k) * HW;
            va[k] = A[idx]; vb[k] = B[idx]; vc[k] = Cc[idx];
            sa += fabsf(va[k]); sb += fabsf(vb[k]); sc += fabsf(vc[k]);
        }
        float* red = (float*)smem4;        // 3*16*16 floats = 3 KB of smem4
        red[(0 * 16 + cg) * 16 + pl] = sa;
        red[(1 * 16 + cg) * 16 + pl] = sb;
        red[(2 * 16 + cg) * 16 + pl] = sc;
        __syncthreads();
        float na = 0.f, nb = 0.f, nc = 0.f;
#pragma unroll
        for (int g = 0; g < 16; ++g) {
            na += red[(0 * 16 + g) * 16 + pl];
            nb += red[(1 * 16 + g) * 16 + pl];
            nc += red[(2 * 16 + g) * 16 + pl];
        }
        const float ra = 1.f / fmaxf(na, 1e-12f);
        const float rb = 1.f / fmaxf(nb, 1e-12f);
        const float rc = 1.f / fmaxf(nc, 1e-12f);

        const size_t obase = ((size_t)bb * HW + p) * NC;
        const int slot = cg ^ pl;          // p&15 == pl (block base is 16-aligned)
        u16x8 xa, xd;
#pragma unroll
        for (int j = 0; j < 8; ++j) {
            xa[j] = f32_to_bf16(va[j] * ra);
            xd[j] = f32_to_bf16(vc[j] * rc - vb[j] * rb);
        }
        *(u16x8*)(anT + obase + slot * 8) = xa;
        *(u16x8*)(dT  + obase + slot * 8) = xd;
    }

    // ---------- Grid barrier (tid0-only fences, relaxed polls) ----------
    __syncthreads();                       // all waves' stores issued & drained
    if (tid == 0) {
        __builtin_amdgcn_fence(__ATOMIC_RELEASE, "agent");  // write back our L2 once
        unsigned long long t = __hip_atomic_fetch_add(
            &g_ctr, 1ULL, __ATOMIC_RELAXED, __HIP_MEMORY_SCOPE_AGENT);
        unsigned long long target = (t / (unsigned long long)NBLK + 1ULL) *
                                    (unsigned long long)NBLK;
        while (__hip_atomic_load(&g_ctr, __ATOMIC_RELAXED,
                                 __HIP_MEMORY_SCOPE_AGENT) < target)
            __builtin_amdgcn_s_sleep(16);
        __builtin_amdgcn_fence(__ATOMIC_ACQUIRE, "agent");  // once, not per poll
    }
    __syncthreads();

    // ---------- Phase 2: persistent-block GEMM ----------
    const int bz = b >> 8;                 // batch
    const int my = (b & 255) >> 3;         // m-tile 0..31
    const int ng = b & 7;                  // n-group: tiles ng*4 .. ng*4+3
    const char* gA  = (const char*)(anT + ((size_t)bz * HW + my * 128) * NC);
    const char* gB0 = (const char*)(dT + ((size_t)bz * HW + ng * 4 * 128) * NC);

    const int wv = tid >> 6;
    const int ln = tid & 63;
    char* buf0 = (char*)smem4;
    char* buf1 = (char*)(smem4 + 2048);

    // Stage A -> buf0, B0 -> buf1 (8 x 16B per thread each, async).
#pragma unroll
    for (int i = 0; i < 8; ++i) {
        const size_t goff = (size_t)(i * 256 + tid) * 16;
        const size_t loff = (size_t)i * 4096 + wv * 1024;  // wave-uniform base
        async_cp16(gA + goff, buf0 + loff);
        async_cp16(gB0 + goff, buf1 + loff);
    }
    __syncthreads();

    const int m16  = ln & 15;
    const int quad = ln >> 4;
    const int wr   = (wv >> 1) * 64;
    const int wc   = (wv & 1) * 64;

    // Hoist this wave's A fragments into registers: 16 x bf16x8 = 64 VGPRs.
    bf16x8 aF[4][4];  // [mi][ks]
#pragma unroll
    for (int ks = 0; ks < 4; ++ks) {
        const int slot = (ks * 4 + quad) ^ m16;
#pragma unroll
        for (int mi = 0; mi < 4; ++mi)
            aF[mi][ks] = *(const bf16x8*)(buf0 + (wr + mi * 16 + m16) * 256 + slot * 16);
    }
    __syncthreads();  // A region free; buf0 becomes B staging

    // Prefetch B1 -> buf0.
#pragma unroll
    for (int i = 0; i < 8; ++i)
        async_cp16(gB0 + 32768 + (size_t)(i * 256 + tid) * 16,
                   buf0 + (size_t)i * 4096 + wv * 1024);

    float s = 0.f;
    for (int j = 0; j < 4; ++j) {
        if (j) {
            __syncthreads();             // drains fill of B_j; frees prev buffer
            if (j < 3) {                 // prefetch B_{j+1} into freed buffer
                char* dst = (j & 1) ? buf1 : buf0;
                const char* src = gB0 + (size_t)(j + 1) * 32768;
#pragma unroll
                for (int i = 0; i < 8; ++i)
                    async_cp16(src + (size_t)(i * 256 + tid) * 16,
                               dst + (size_t)i * 4096 + wv * 1024);
            }
        }
        const char* sB = (j & 1) ? buf0 : buf1;
        f32x4 acc[4][4] = {};
#pragma unroll
        for (int ks = 0; ks < 4; ++ks) {
            const int slot = (ks * 4 + quad) ^ m16;
            bf16x8 bfr[4];
#pragma unroll
            for (int ni = 0; ni < 4; ++ni)
                bfr[ni] = *(const bf16x8*)(sB + (wc + ni * 16 + m16) * 256 + slot * 16);
#pragma unroll
            for (int mi = 0; mi < 4; ++mi)
#pragma unroll
                for (int ni = 0; ni < 4; ++ni)
                    acc[mi][ni] = __builtin_amdgcn_mfma_f32_16x16x32_bf16(
                        aF[mi][ks], bfr[ni], acc[mi][ni], 0, 0, 0);
        }
#pragma unroll
        for (int mi = 0; mi < 4; ++mi)
#pragma unroll
            for (int ni = 0; ni < 4; ++ni)
#pragma unroll
                for (int r = 0; r < 4; ++r)
                    s += fabsf(acc[mi][ni][r]);
    }

#pragma unroll
    for (int off = 32; off > 0; off >>= 1)
        s += __shfl_down(s, off);
    __syncthreads();
    if (ln == 0) ((float*)smem4)[wv] = s;
    __syncthreads();
    if (tid == 0) {
        const float inv = 1.0f / ((float)BATCH * (float)HW * (float)HW);
        float t = ((float*)smem4)[0] + ((float*)smem4)[1] +
                  ((float*)smem4)[2] + ((float*)smem4)[3];
        atomicAdd(out, t * inv);
    }
}

extern "C" void kernel_launch(void* const* d_in, const int* in_sizes, int n_in,
                              void* d_out, int out_size, void* d_ws, size_t ws_size,
                              hipStream_t stream) {
    const float* A  = (const float*)d_in[0];
    const float* B  = (const float*)d_in[1];
    const float* Cc = (const float*)d_in[2];
    float* out = (float*)d_out;
    unsigned short* anT = (unsigned short*)d_ws;                 // 2 MB
    unsigned short* dT  = anT + (size_t)BATCH * HW * NC;         // 2 MB

    fused_kernel<<<dim3(NBLK), dim3(256), 0, stream>>>(A, B, Cc, anT, dT, out);
}

// Round 8
// 80.855 us; speedup vs baseline: 2.3593x; 1.3859x over previous
//
#include <hip/hip_runtime.h>
#include <stdint.h>

#define HW 4096
#define NC 128
#define BATCH 2
#define NBLK 512
#define FLAG_DONE 1u

typedef __attribute__((ext_vector_type(8))) short bf16x8;
typedef __attribute__((ext_vector_type(4))) float f32x4;
typedef __attribute__((ext_vector_type(8))) unsigned short u16x8;

__device__ __forceinline__ unsigned short f32_to_bf16(float f) {
    union { float f; unsigned int u; } v; v.f = f;
    unsigned int u = v.u;
    unsigned int r = (u + 0x7FFFu + ((u >> 16) & 1u)) >> 16;
    return (unsigned short)r;
}

// Async global->LDS, 16B/lane. LDS dest = wave-uniform base + lane*16 (m104).
__device__ __forceinline__ void async_cp16(const void* g, void* s) {
    __builtin_amdgcn_global_load_lds(
        (const __attribute__((address_space(1))) uint32_t*)g,
        (__attribute__((address_space(3))) uint32_t*)s, 16, 0, 0);
}

// Per-wave poll: lane ln watches flags[watch] (watch<0 = nothing). First check
// exits immediately in the common already-set case. Relaxed agent loads bypass
// the non-coherent per-XCD L2; no fences (see release/freshness argument in
// kernel comment). Flags padded to 64B (16 uints) to avoid L3 line contention.
__device__ __forceinline__ void wait_flags(const unsigned int* flags, int watch) {
    bool done = (watch < 0);
    while (true) {
        if (!done && __hip_atomic_load(&flags[watch], __ATOMIC_RELAXED,
                                       __HIP_MEMORY_SCOPE_AGENT) == FLAG_DONE)
            done = true;
        if (__all(done)) break;
        __builtin_amdgcn_s_sleep(1);
    }
}

// Fused norm + GEMM with producer-flag sync (no grid barrier):
//  phase 1: block b L1-normalizes positions [b*16, b*16+16), writes a_n and
//    d = c_n - b_n transposed to [b][pos][c] bf16 (16B-chunk swizzle
//    slot = chunk ^ (pos&15)) via AGENT-SCOPE 8B atomic stores (bypass L2 ->
//    coherent at L3; no release fence / buffer_wbl2 needed). __syncthreads
//    drains vmcnt, then tid0 stores flag[b]=1 (plain agent store, no RMW —
//    R7's 512-way same-address fetch_add serialization was the ~40us stall).
//  phase 2: persistent 128x128 GEMM tile group; consumer waits only on the
//    8 A-panel producers + 8 producers of each B tile (+ flag[0] which orders
//    block 0's *out=0), polled per-wave in parallel lanes. Deadlock-free under
//    any scheduling: flags are set before any wait.
__global__ __launch_bounds__(256, 2) void fused_kernel(
    const float* __restrict__ A, const float* __restrict__ B,
    const float* __restrict__ Cc,
    unsigned short* __restrict__ anT, unsigned short* __restrict__ dT,
    unsigned int* __restrict__ flags, float* __restrict__ out) {
    __shared__ uint4 smem4[4096];  // 64 KB, overlaid: norm-reduce then GEMM bufs
    const int tid = threadIdx.x;
    const int b   = blockIdx.x;    // 0..511

    if (b == 0 && tid == 0)        // bypassing store; ordered by flag[0]
        __hip_atomic_store(out, 0.f, __ATOMIC_RELAXED, __HIP_MEMORY_SCOPE_AGENT);

    // ---------- Phase 1: norm + transpose (16 positions per block) ----------
    {
        const int pl = tid & 15;           // position lane 0..15
        const int cg = tid >> 4;           // channel group 0..15 (8 ch each)
        const int gp = b * 16;             // 512*16 = 8192 positions
        const int bb = gp >> 12;           // batch
        const int p  = (gp & (HW - 1)) + pl;
        const size_t base = (size_t)bb * NC * HW + p;  // + c*HW -> x[b][c][p]
        const int c0 = cg * 8;

        float va[8], vb[8], vc[8];
        float sa = 0.f, sb = 0.f, sc = 0.f;
#pragma unroll
        for (int k = 0; k < 8; ++k) {
            size_t idx = base + (size_t)(c0 + k) * HW;
            va[k] = A[idx]; vb[k] = B[idx]; vc[k] = Cc[idx];
            sa += fabsf(va[k]); sb += fabsf(vb[k]); sc += fabsf(vc[k]);
        }
        float* red = (float*)smem4;        // 3*16*16 floats = 3 KB of smem4
        red[(0 * 16 + cg) * 16 + pl] = sa;
        red[(1 * 16 + cg) * 16 + pl] = sb;
        red[(2 * 16 + cg) * 16 + pl] = sc;
        __syncthreads();
        float na = 0.f, nb = 0.f, nc = 0.f;
#pragma unroll
        for (int g = 0; g < 16; ++g) {
            na += red[(0 * 16 + g) * 16 + pl];
            nb += red[(1 * 16 + g) * 16 + pl];
            nc += red[(2 * 16 + g) * 16 + pl];
        }
        const float ra = 1.f / fmaxf(na, 1e-12f);
        const float rb = 1.f / fmaxf(nb, 1e-12f);
        const float rc = 1.f / fmaxf(nc, 1e-12f);

        const size_t obase = ((size_t)bb * HW + p) * NC;
        const int slot = cg ^ pl;          // p&15 == pl (block base is 16-aligned)
        union { u16x8 v; unsigned long long q[2]; } xa, xd;
#pragma unroll
        for (int j = 0; j < 8; ++j) {
            xa.v[j] = f32_to_bf16(va[j] * ra);
            xd.v[j] = f32_to_bf16(vc[j] * rc - vb[j] * rb);
        }
        unsigned long long* pa8 = (unsigned long long*)(anT + obase) + slot * 2;
        unsigned long long* pd8 = (unsigned long long*)(dT  + obase) + slot * 2;
        __hip_atomic_store(pa8,     xa.q[0], __ATOMIC_RELAXED, __HIP_MEMORY_SCOPE_AGENT);
        __hip_atomic_store(pa8 + 1, xa.q[1], __ATOMIC_RELAXED, __HIP_MEMORY_SCOPE_AGENT);
        __hip_atomic_store(pd8,     xd.q[0], __ATOMIC_RELAXED, __HIP_MEMORY_SCOPE_AGENT);
        __hip_atomic_store(pd8 + 1, xd.q[1], __ATOMIC_RELAXED, __HIP_MEMORY_SCOPE_AGENT);
    }

    __syncthreads();                       // vmcnt(0): all bypassing stores visible
    if (tid == 0)                          // publish: plain agent store, no RMW
        __hip_atomic_store(&flags[b * 16], FLAG_DONE,
                           __ATOMIC_RELAXED, __HIP_MEMORY_SCOPE_AGENT);

    // ---------- Phase 2: persistent-block GEMM ----------
    const int bz = b >> 8;                 // batch
    const int my = (b & 255) >> 3;         // m-tile 0..31
    const int ng = b & 7;                  // n-group: tiles ng*4 .. ng*4+3
    const char* gA  = (const char*)(anT + ((size_t)bz * HW + my * 128) * NC);
    const char* gB0 = (const char*)(dT + ((size_t)bz * HW + ng * 4 * 128) * NC);
    const int pa  = (bz << 8) + my * 8;    // A-panel producer blocks pa..pa+7
    const int pb  = (bz << 8) + ng * 32;   // B-tile j producers pb+j*8 .. +7

    const int wv = tid >> 6;
    const int ln = tid & 63;
    char* buf0 = (char*)smem4;
    char* buf1 = (char*)(smem4 + 2048);

    // Wait for A producers (lanes 0-7), B0 producers (lanes 8-15), block 0
    // (lane 16, orders *out=0). Every wave polls before issuing its loads.
    {
        int watch = -1;
        if (ln < 8)       watch = (pa + ln) * 16;
        else if (ln < 16) watch = (pb + (ln - 8)) * 16;
        else if (ln == 16) watch = 0;
        wait_flags(flags, watch);
    }

    // Stage A -> buf0, B0 -> buf1 (8 x 16B per thread each, async).
#pragma unroll
    for (int i = 0; i < 8; ++i) {
        const size_t goff = (size_t)(i * 256 + tid) * 16;
        const size_t loff = (size_t)i * 4096 + wv * 1024;  // wave-uniform base
        async_cp16(gA + goff, buf0 + loff);
        async_cp16(gB0 + goff, buf1 + loff);
    }
    __syncthreads();

    const int m16  = ln & 15;
    const int quad = ln >> 4;
    const int wr   = (wv >> 1) * 64;
    const int wc   = (wv & 1) * 64;

    // Hoist this wave's A fragments into registers: 16 x bf16x8 = 64 VGPRs.
    bf16x8 aF[4][4];  // [mi][ks]
#pragma unroll
    for (int ks = 0; ks < 4; ++ks) {
        const int slot = (ks * 4 + quad) ^ m16;
#pragma unroll
        for (int mi = 0; mi < 4; ++mi)
            aF[mi][ks] = *(const bf16x8*)(buf0 + (wr + mi * 16 + m16) * 256 + slot * 16);
    }
    __syncthreads();  // A region free; buf0 becomes B staging

    // Wait for B1 producers, then prefetch B1 -> buf0.
    wait_flags(flags, (ln < 8) ? (pb + 8 + ln) * 16 : -1);
#pragma unroll
    for (int i = 0; i < 8; ++i)
        async_cp16(gB0 + 32768 + (size_t)(i * 256 + tid) * 16,
                   buf0 + (size_t)i * 4096 + wv * 1024);

    float s = 0.f;
    for (int j = 0; j < 4; ++j) {
        if (j) {
            __syncthreads();             // drains fill of B_j; frees prev buffer
            if (j < 3) {                 // wait producers, prefetch B_{j+1}
                wait_flags(flags, (ln < 8) ? (pb + (j + 1) * 8 + ln) * 16 : -1);
                char* dst = (j & 1) ? buf1 : buf0;
                const char* src = gB0 + (size_t)(j + 1) * 32768;
#pragma unroll
                for (int i = 0; i < 8; ++i)
                    async_cp16(src + (size_t)(i * 256 + tid) * 16,
                               dst + (size_t)i * 4096 + wv * 1024);
            }
        }
        const char* sB = (j & 1) ? buf0 : buf1;
        f32x4 acc[4][4] = {};
#pragma unroll
        for (int ks = 0; ks < 4; ++ks) {
            const int slot = (ks * 4 + quad) ^ m16;
            bf16x8 bfr[4];
#pragma unroll
            for (int ni = 0; ni < 4; ++ni)
                bfr[ni] = *(const bf16x8*)(sB + (wc + ni * 16 + m16) * 256 + slot * 16);
#pragma unroll
            for (int mi = 0; mi < 4; ++mi)
#pragma unroll
                for (int ni = 0; ni < 4; ++ni)
                    acc[mi][ni] = __builtin_amdgcn_mfma_f32_16x16x32_bf16(
                        aF[mi][ks], bfr[ni], acc[mi][ni], 0, 0, 0);
        }
#pragma unroll
        for (int mi = 0; mi < 4; ++mi)
#pragma unroll
            for (int ni = 0; ni < 4; ++ni)
#pragma unroll
                for (int r = 0; r < 4; ++r)
                    s += fabsf(acc[mi][ni][r]);
    }

#pragma unroll
    for (int off = 32; off > 0; off >>= 1)
        s += __shfl_down(s, off);
    __syncthreads();
    if (ln == 0) ((float*)smem4)[wv] = s;
    __syncthreads();
    if (tid == 0) {
        const float inv = 1.0f / ((float)BATCH * (float)HW * (float)HW);
        float t = ((float*)smem4)[0] + ((float*)smem4)[1] +
                  ((float*)smem4)[2] + ((float*)smem4)[3];
        atomicAdd(out, t * inv);
    }
}

extern "C" void kernel_launch(void* const* d_in, const int* in_sizes, int n_in,
                              void* d_out, int out_size, void* d_ws, size_t ws_size,
                              hipStream_t stream) {
    const float* A  = (const float*)d_in[0];
    const float* B  = (const float*)d_in[1];
    const float* Cc = (const float*)d_in[2];
    float* out = (float*)d_out;
    unsigned short* anT = (unsigned short*)d_ws;                 // 2 MB
    unsigned short* dT  = anT + (size_t)BATCH * HW * NC;         // 2 MB
    // Flags: 512 x 16 uints (64B padded), after the 4 MB of anT/dT. Poisoned
    // to 0xAAAAAAAA (!= FLAG_DONE) by the harness before every launch.
    unsigned int* flags = (unsigned int*)(dT + (size_t)BATCH * HW * NC);

    fused_kernel<<<dim3(NBLK), dim3(256), 0, stream>>>(A, B, Cc, anT, dT,
                                                       flags, out);
}